// Round 3
// baseline (2202.243 us; speedup 1.0000x reference)
//
#include <hip/hip_runtime.h>

typedef unsigned short u16;
typedef __attribute__((ext_vector_type(8))) short short8;
typedef __attribute__((ext_vector_type(8))) __bf16 bf16x8;
typedef __attribute__((ext_vector_type(4))) float f32x4;

#define DEV __device__ __forceinline__

DEV float bf2f(u16 u) {
    union { unsigned v; float f; } x; x.v = ((unsigned)u) << 16; return x.f;
}
DEV u16 f2bf(float f) {
    union { float f; unsigned v; } x; x.f = f;
    unsigned r = x.v + 0x7fff + ((x.v >> 16) & 1);
    return (u16)(r >> 16);
}

DEV f32x4 mfma16(short8 a, short8 b, f32x4 c) {
    return __builtin_amdgcn_mfma_f32_16x16x32_bf16(
        __builtin_bit_cast(bf16x8, a), __builtin_bit_cast(bf16x8, b), c, 0, 0, 0);
}

typedef const __attribute__((address_space(1))) void* gas_ptr;
typedef __attribute__((address_space(3))) void* las_ptr;

// ---------------- LayerNorm: one block per row of D=2048; f32 in, bf16 out ----------------
__global__ __launch_bounds__(256) void ln_kernel(
    const float* __restrict__ x, const float* __restrict__ sc, const float* __restrict__ sh,
    u16* __restrict__ out)
{
    int row = blockIdx.x, tid = threadIdx.x;
    const f32x4* xr = (const f32x4*)(x + (size_t)row * 2048 + tid * 8);
    f32x4 a = xr[0], b = xr[1];
    float f[8], sum = 0.f, ss = 0.f;
#pragma unroll
    for (int j = 0; j < 4; j++) { f[j] = a[j]; f[4 + j] = b[j]; }
#pragma unroll
    for (int j = 0; j < 8; j++) { sum += f[j]; ss += f[j] * f[j]; }
#pragma unroll
    for (int m = 1; m < 64; m <<= 1) { sum += __shfl_xor(sum, m, 64); ss += __shfl_xor(ss, m, 64); }
    __shared__ float red[8];
    int w = tid >> 6, l = tid & 63;
    if (l == 0) { red[w] = sum; red[4 + w] = ss; }
    __syncthreads();
    sum = red[0] + red[1] + red[2] + red[3];
    ss  = red[4] + red[5] + red[6] + red[7];
    float mean = sum * (1.f / 2048.f);
    float var  = ss * (1.f / 2048.f) - mean * mean;
    float rstd = rsqrtf(var + 1e-5f);
    const f32x4* sp = (const f32x4*)(sc + tid * 8);
    const f32x4* bp = (const f32x4*)(sh + tid * 8);
    f32x4 s0 = sp[0], s1 = sp[1], b0 = bp[0], b1 = bp[1];
    short8 o;
#pragma unroll
    for (int j = 0; j < 4; j++) {
        o[j]     = (short)f2bf((f[j] - mean) * rstd * s0[j] + b0[j]);
        o[4 + j] = (short)f2bf((f[4 + j] - mean) * rstd * s1[j] + b1[j]);
    }
    *(short8*)(out + (size_t)row * 2048 + tid * 8) = o;
}

// ---------------- GEMM: C(MxN) = A(MxK)[bf16] * B(KxN)[f32 row-major] ----------------
// EPI: 0 = plain, 1 = +bias +residual(f32), 2 = +bias +gelu ; OUTF: 1 = f32 out, 0 = bf16 out
template<int EPI, int OUTF>
__global__ __launch_bounds__(256, 2) void gemm_kernel(
    const u16* __restrict__ A, const float* __restrict__ Bm, void* __restrict__ Cp,
    const float* __restrict__ bias, const float* __restrict__ res, int M, int N, int K)
{
    __shared__ u16 As[2][128 * 32];
    __shared__ u16 Bs[2][128 * 32];
    int tid = threadIdx.x, l = tid & 63, w = tid >> 6;
    int mbase = blockIdx.y * 128, nbase = blockIdx.x * 128;
    int NK = K >> 5;

    auto stageA = [&](int kt, int bufi) {
#pragma unroll
        for (int c = 0; c < 2; c++) {
            int slot = c * 256 + w * 64 + l;
            const u16* g = A + (size_t)(mbase + (slot >> 2)) * K + kt * 32 + (slot & 3) * 8;
            u16* ldst = &As[bufi][(c * 256 + w * 64) * 8];
            __builtin_amdgcn_global_load_lds((gas_ptr)g, (las_ptr)ldst, 16, 0, 0);
        }
    };
    auto loadB = [&](int kt, short8* br) {
#pragma unroll
        for (int c = 0; c < 2; c++) {
            int slot = c * 256 + tid;
            const float* g = Bm + (size_t)(kt * 32 + (slot >> 4)) * N + nbase + (slot & 15) * 8;
            f32x4 u0 = *(const f32x4*)g;
            f32x4 u1 = *(const f32x4*)(g + 4);
            short8 t;
#pragma unroll
            for (int j = 0; j < 4; j++) { t[j] = (short)f2bf(u0[j]); t[4 + j] = (short)f2bf(u1[j]); }
            br[c] = t;
        }
    };
    auto writeB = [&](int bufi, short8* br) {
#pragma unroll
        for (int c = 0; c < 2; c++) {
            int slot = c * 256 + tid, kk = slot >> 4, nseg = slot & 15;
#pragma unroll
            for (int j = 0; j < 8; j++) Bs[bufi][(nseg * 8 + j) * 32 + kk] = (u16)br[c][j];
        }
    };

    f32x4 acc[4][4];
#pragma unroll
    for (int i = 0; i < 4; i++)
#pragma unroll
        for (int j = 0; j < 4; j++) acc[i][j] = (f32x4){0.f, 0.f, 0.f, 0.f};
    int wr = (w >> 1) * 64, wc = (w & 1) * 64;

    short8 br0[2];
    stageA(0, 0); loadB(0, br0); writeB(0, br0);
    __syncthreads();
    int buf = 0;
    for (int kt = 0; kt < NK; ++kt) {
        short8 brn[2];
        if (kt + 1 < NK) { stageA(kt + 1, buf ^ 1); loadB(kt + 1, brn); }
        short8 af[4], bfr[4];
#pragma unroll
        for (int i = 0; i < 4; i++) {
            af[i]  = *(const short8*)&As[buf][(wr + i * 16 + (l & 15)) * 32 + (l >> 4) * 8];
            bfr[i] = *(const short8*)&Bs[buf][(wc + i * 16 + (l & 15)) * 32 + (l >> 4) * 8];
        }
#pragma unroll
        for (int mi = 0; mi < 4; mi++)
#pragma unroll
            for (int ni = 0; ni < 4; ni++)
                acc[mi][ni] = mfma16(af[mi], bfr[ni], acc[mi][ni]);
        if (kt + 1 < NK) writeB(buf ^ 1, brn);
        __syncthreads();
        buf ^= 1;
    }

#pragma unroll
    for (int mi = 0; mi < 4; mi++) {
#pragma unroll
        for (int ni = 0; ni < 4; ni++) {
            int col = nbase + wc + ni * 16 + (l & 15);
            float bval = (EPI != 0) ? bias[col] : 0.f;
#pragma unroll
            for (int r = 0; r < 4; r++) {
                int row = mbase + wr + mi * 16 + (l >> 4) * 4 + r;
                float v = acc[mi][ni][r];
                if (EPI == 1) v += bval + res[(size_t)row * N + col];
                if (EPI == 2) {
                    v += bval;
                    float t = tanhf(0.7978845608028654f * (v + 0.044715f * v * v * v));
                    v = 0.5f * v * (1.f + t);
                }
                if (OUTF) ((float*)Cp)[(size_t)row * N + col] = v;
                else      ((u16*)Cp)[(size_t)row * N + col] = f2bf(v);
            }
        }
    }
}

// ---------------- Causal flash attention: H=16, HD=128, S=2048, bf16 in/out ----------------
// grid: (S/64, B*H); block 256 (4 waves x 16 q-rows)
__global__ __launch_bounds__(256, 2) void attn_kernel(
    const u16* __restrict__ Q, const u16* __restrict__ Kp, const u16* __restrict__ Vp,
    u16* __restrict__ O)
{
    __shared__ u16 Ks[64 * 128];
    __shared__ u16 VT[128 * 64];
    __shared__ u16 Ps[4 * 16 * 32];
    int tid = threadIdx.x, l = tid & 63, w = tid >> 6;
    int qt = blockIdx.x, bh = blockIdx.y, b = bh >> 4, h = bh & 15;
    const float SCALE = 0.08838834764831845f; // 1/sqrt(128)
    int qbase = qt * 64;
    size_t bS = (size_t)b * 2048;

    short8 qf[4];
    {
        int qrow = qbase + w * 16 + (l & 15);
        const u16* qp = Q + (bS + qrow) * 2048 + h * 128 + (l >> 4) * 8;
#pragma unroll
        for (int ds = 0; ds < 4; ds++) qf[ds] = *(const short8*)(qp + ds * 32);
    }
    float m_[4], l_[4];
    f32x4 o_[8];
#pragma unroll
    for (int r = 0; r < 4; r++) { m_[r] = -1e30f; l_[r] = 0.f; }
#pragma unroll
    for (int d = 0; d < 8; d++) o_[d] = (f32x4){0.f, 0.f, 0.f, 0.f};

    for (int kt = 0; kt <= qt; ++kt) {
        int kbase = kt * 64;
#pragma unroll
        for (int it = 0; it < 4; ++it) {
            int slot = it * 256 + tid;
            int key = slot >> 4, dseg = slot & 15;
            const u16* kp = Kp + (bS + kbase + key) * 2048 + h * 128 + dseg * 8;
            short8 kv = *(const short8*)kp;
            int kidx = ((key * 256 + dseg * 16) ^ ((key & 7) << 4)) >> 1;
            *(short8*)&Ks[kidx] = kv;
            const u16* vp = Vp + (bS + kbase + key) * 2048 + h * 128 + dseg * 8;
            short8 vv = *(const short8*)vp;
#pragma unroll
            for (int j = 0; j < 8; j++) {
                int d = dseg * 8 + j;
                int vidx = ((d * 128 + key * 2) ^ ((d & 7) << 4)) >> 1;
                VT[vidx] = (u16)vv[j];
            }
        }
        __syncthreads();

#pragma unroll
        for (int hh = 0; hh < 2; ++hh) {
            f32x4 s0 = {0.f, 0.f, 0.f, 0.f}, s1 = {0.f, 0.f, 0.f, 0.f};
            int key0 = hh * 32 + (l & 15);
            int dl = (l >> 4) * 8;
#pragma unroll
            for (int ds = 0; ds < 4; ds++) {
                int d2 = (ds * 32 + dl) * 2;
                int i0 = ((key0 * 256 + d2) ^ ((key0 & 7) << 4)) >> 1;
                int i1 = (((key0 + 16) * 256 + d2) ^ (((key0 + 16) & 7) << 4)) >> 1;
                short8 k0v = *(const short8*)&Ks[i0];
                short8 k1v = *(const short8*)&Ks[i1];
                s0 = mfma16(qf[ds], k0v, s0);
                s1 = mfma16(qf[ds], k1v, s1);
            }
            int qr0 = qbase + w * 16 + (l >> 4) * 4;
            int kc0 = kbase + hh * 32 + (l & 15);
            float alpha[4];
#pragma unroll
            for (int r = 0; r < 4; r++) {
                float a0 = s0[r] * SCALE; if (kc0 > qr0 + r) a0 = -1e30f;
                float a1 = s1[r] * SCALE; if (kc0 + 16 > qr0 + r) a1 = -1e30f;
                float t = fmaxf(a0, a1);
                t = fmaxf(t, __shfl_xor(t, 1, 64));
                t = fmaxf(t, __shfl_xor(t, 2, 64));
                t = fmaxf(t, __shfl_xor(t, 4, 64));
                t = fmaxf(t, __shfl_xor(t, 8, 64));
                float mn = fmaxf(m_[r], t);
                alpha[r] = __expf(m_[r] - mn);
                m_[r] = mn;
                float p0 = __expf(a0 - mn), p1 = __expf(a1 - mn);
                float rs = p0 + p1;
                rs += __shfl_xor(rs, 1, 64);
                rs += __shfl_xor(rs, 2, 64);
                rs += __shfl_xor(rs, 4, 64);
                rs += __shfl_xor(rs, 8, 64);
                l_[r] = l_[r] * alpha[r] + rs;
                int prow = (l >> 4) * 4 + r;
                u16* Pw = &Ps[w * 512];
                int ia = ((prow * 64 + (l & 15) * 2) ^ ((prow & 3) << 4)) >> 1;
                int ib = ((prow * 64 + (16 + (l & 15)) * 2) ^ ((prow & 3) << 4)) >> 1;
                Pw[ia] = f2bf(p0);
                Pw[ib] = f2bf(p1);
            }
            asm volatile("s_waitcnt lgkmcnt(0)" ::: "memory");
#pragma unroll
            for (int dblk = 0; dblk < 8; dblk++)
#pragma unroll
                for (int r = 0; r < 4; r++) o_[dblk][r] *= alpha[r];
            int prow = l & 15;
            int ia = ((prow * 64 + dl * 2) ^ ((prow & 3) << 4)) >> 1;
            short8 pa = *(const short8*)&Ps[w * 512 + ia];
#pragma unroll
            for (int dblk = 0; dblk < 8; dblk++) {
                int d = dblk * 16 + (l & 15);
                int key = hh * 32 + dl;
                int iv = ((d * 128 + key * 2) ^ ((d & 7) << 4)) >> 1;
                short8 vb = *(const short8*)&VT[iv];
                o_[dblk] = mfma16(pa, vb, o_[dblk]);
            }
        }
        __syncthreads();
    }

#pragma unroll
    for (int dblk = 0; dblk < 8; dblk++) {
#pragma unroll
        for (int r = 0; r < 4; r++) {
            int qrow = qbase + w * 16 + (l >> 4) * 4 + r;
            float v = o_[dblk][r] / l_[r];
            O[(bS + qrow) * 2048 + h * 128 + dblk * 16 + (l & 15)] = f2bf(v);
        }
    }
}

extern "C" void kernel_launch(void* const* d_in, const int* in_sizes, int n_in,
                              void* d_out, int out_size, void* d_ws, size_t ws_size,
                              hipStream_t stream)
{
    const float* x    = (const float*)d_in[0];
    const float* ln1s = (const float*)d_in[1];
    const float* ln1b = (const float*)d_in[2];
    const float* Wq   = (const float*)d_in[3];
    const float* Wk   = (const float*)d_in[4];
    const float* Wv   = (const float*)d_in[5];
    const float* Wo   = (const float*)d_in[6];
    const float* bo   = (const float*)d_in[7];
    const float* ln2s = (const float*)d_in[8];
    const float* ln2b = (const float*)d_in[9];
    const float* W1   = (const float*)d_in[10];
    const float* b1   = (const float*)d_in[11];
    const float* W2   = (const float*)d_in[12];
    const float* b2   = (const float*)d_in[13];
    float* out = (float*)d_out;   // reference output dtype is float32
    const size_t ACT = (size_t)2 * 2048 * 2048; // 8388608 elems

    u16* xn    = (u16*)d_ws;        // [0, ACT) bf16 — later reused as ctx
    u16* q     = xn + ACT;          // [ACT, 2ACT) bf16 — later reused as xn2
    u16* k     = xn + 2 * ACT;      // [2ACT, 3ACT)
    u16* v     = xn + 3 * ACT;      // [3ACT, 4ACT)
    u16* hbuf  = xn + 2 * ACT;      // [2ACT, 6ACT) bf16 — k,v dead by then
    float* x2  = (float*)(xn + 6 * ACT); // f32, [6ACT*2B, +4ACT*4B)

    dim3 blk(256);
    ln_kernel<<<4096, blk, 0, stream>>>(x, ln1s, ln1b, xn);
    gemm_kernel<0, 0><<<dim3(16, 32), blk, 0, stream>>>(xn, Wq, q, nullptr, nullptr, 4096, 2048, 2048);
    gemm_kernel<0, 0><<<dim3(16, 32), blk, 0, stream>>>(xn, Wk, k, nullptr, nullptr, 4096, 2048, 2048);
    gemm_kernel<0, 0><<<dim3(16, 32), blk, 0, stream>>>(xn, Wv, v, nullptr, nullptr, 4096, 2048, 2048);
    attn_kernel<<<dim3(32, 32), blk, 0, stream>>>(q, k, v, xn); // ctx -> xn
    gemm_kernel<1, 1><<<dim3(16, 32), blk, 0, stream>>>(xn, Wo, x2, bo, x, 4096, 2048, 2048);
    ln_kernel<<<4096, blk, 0, stream>>>(x2, ln2s, ln2b, q);     // xn2 -> q
    gemm_kernel<2, 0><<<dim3(64, 32), blk, 0, stream>>>(q, W1, hbuf, b1, nullptr, 4096, 8192, 2048);
    gemm_kernel<1, 1><<<dim3(16, 32), blk, 0, stream>>>(hbuf, W2, out, b2, x2, 4096, 2048, 8192);
}

// Round 4
// 1003.611 us; speedup vs baseline: 2.1943x; 2.1943x over previous
//
#include <hip/hip_runtime.h>

typedef unsigned short u16;
typedef __attribute__((ext_vector_type(8))) short short8;
typedef __attribute__((ext_vector_type(8))) __bf16 bf16x8;
typedef __attribute__((ext_vector_type(4))) float f32x4;

#define DEV __device__ __forceinline__

DEV float bf2f(u16 u) {
    union { unsigned v; float f; } x; x.v = ((unsigned)u) << 16; return x.f;
}
DEV u16 f2bf(float f) {
    union { float f; unsigned v; } x; x.f = f;
    unsigned r = x.v + 0x7fff + ((x.v >> 16) & 1);
    return (u16)(r >> 16);
}

DEV f32x4 mfma16(short8 a, short8 b, f32x4 c) {
    return __builtin_amdgcn_mfma_f32_16x16x32_bf16(
        __builtin_bit_cast(bf16x8, a), __builtin_bit_cast(bf16x8, b), c, 0, 0, 0);
}

typedef const __attribute__((address_space(1))) void* gas_ptr;
typedef __attribute__((address_space(3))) void* las_ptr;

// ---------------- Transpose: f32 [R][C] -> bf16 [C][R] ----------------
// grid (C/64, R/64), block 256
__global__ __launch_bounds__(256) void transpose_kernel(
    const float* __restrict__ in, u16* __restrict__ out, int R, int C)
{
    __shared__ u16 t[64][65];
    int tid = threadIdx.x;
    int bc = blockIdx.x * 64, br = blockIdx.y * 64;
    int r = tid >> 2, cs = (tid & 3) * 16;
    const float* ip = in + (size_t)(br + r) * C + bc + cs;
    f32x4 v0 = *(const f32x4*)ip, v1 = *(const f32x4*)(ip + 4),
          v2 = *(const f32x4*)(ip + 8), v3 = *(const f32x4*)(ip + 12);
#pragma unroll
    for (int j = 0; j < 4; j++) {
        t[r][cs + j]      = f2bf(v0[j]);
        t[r][cs + 4 + j]  = f2bf(v1[j]);
        t[r][cs + 8 + j]  = f2bf(v2[j]);
        t[r][cs + 12 + j] = f2bf(v3[j]);
    }
    __syncthreads();
    int n = tid >> 2, ks = (tid & 3) * 16;
    short8 o0, o1;
#pragma unroll
    for (int j = 0; j < 8; j++) { o0[j] = (short)t[ks + j][n]; o1[j] = (short)t[ks + 8 + j][n]; }
    u16* op = out + (size_t)(bc + n) * R + br + ks;
    *(short8*)op = o0;
    *(short8*)(op + 8) = o1;
}

// ---------------- LayerNorm: one block per row of D=2048; f32/bf16 in, bf16 out ----------------
template<int INBF>
__global__ __launch_bounds__(256) void ln_kernel(
    const void* __restrict__ xp, const float* __restrict__ sc, const float* __restrict__ sh,
    u16* __restrict__ out)
{
    int row = blockIdx.x, tid = threadIdx.x;
    float f[8], sum = 0.f, ss = 0.f;
    if (INBF) {
        short8 v = *(const short8*)((const u16*)xp + (size_t)row * 2048 + tid * 8);
#pragma unroll
        for (int j = 0; j < 8; j++) f[j] = bf2f((u16)v[j]);
    } else {
        const f32x4* xr = (const f32x4*)((const float*)xp + (size_t)row * 2048 + tid * 8);
        f32x4 a = xr[0], b = xr[1];
#pragma unroll
        for (int j = 0; j < 4; j++) { f[j] = a[j]; f[4 + j] = b[j]; }
    }
#pragma unroll
    for (int j = 0; j < 8; j++) { sum += f[j]; ss += f[j] * f[j]; }
#pragma unroll
    for (int m = 1; m < 64; m <<= 1) { sum += __shfl_xor(sum, m, 64); ss += __shfl_xor(ss, m, 64); }
    __shared__ float red[8];
    int w = tid >> 6, l = tid & 63;
    if (l == 0) { red[w] = sum; red[4 + w] = ss; }
    __syncthreads();
    sum = red[0] + red[1] + red[2] + red[3];
    ss  = red[4] + red[5] + red[6] + red[7];
    float mean = sum * (1.f / 2048.f);
    float var  = ss * (1.f / 2048.f) - mean * mean;
    float rstd = rsqrtf(var + 1e-5f);
    const f32x4* sp = (const f32x4*)(sc + tid * 8);
    const f32x4* bp = (const f32x4*)(sh + tid * 8);
    f32x4 s0 = sp[0], s1 = sp[1], b0 = bp[0], b1 = bp[1];
    short8 o;
#pragma unroll
    for (int j = 0; j < 4; j++) {
        o[j]     = (short)f2bf((f[j] - mean) * rstd * s0[j] + b0[j]);
        o[4 + j] = (short)f2bf((f[4 + j] - mean) * rstd * s1[j] + b1[j]);
    }
    *(short8*)(out + (size_t)row * 2048 + tid * 8) = o;
}

// ---------------- GEMM: C(MxN) = A(MxK)[bf16] * BT(NxK)[bf16] ----------------
// EPI: 0 plain, 1 +bias+residual, 2 +bias+gelu ; OUTF: 1 f32 out ; RESBF: residual bf16
// SPLIT3: write into 3 consecutive ACT-sized buffers by col>>11 (QKV fusion)
template<int EPI, int OUTF, int RESBF, int SPLIT3>
__global__ __launch_bounds__(256, 2) void gemm_bt(
    const u16* __restrict__ A, const u16* __restrict__ BT, void* __restrict__ Cp,
    const float* __restrict__ bias, const void* __restrict__ res, int M, int N, int K)
{
    __shared__ u16 As[2][128 * 32];
    __shared__ u16 Bs[2][128 * 32];
    int tid = threadIdx.x, l = tid & 63, w = tid >> 6;
    int mbase = blockIdx.y * 128, nbase = blockIdx.x * 128;
    int NK = K >> 5;
    const u16* Ag = A + (size_t)mbase * K;
    const u16* Bg = BT + (size_t)nbase * K;

    auto stage = [&](const u16* G, u16* Ld, int kt) {
#pragma unroll
        for (int c = 0; c < 2; c++) {
            int slot = c * 256 + w * 64 + l;
            const u16* g = G + (size_t)(slot >> 2) * K + kt * 32 + (slot & 3) * 8;
            __builtin_amdgcn_global_load_lds((gas_ptr)g, (las_ptr)(Ld + (c * 256 + w * 64) * 8), 16, 0, 0);
        }
    };

    f32x4 acc[4][4];
#pragma unroll
    for (int i = 0; i < 4; i++)
#pragma unroll
        for (int j = 0; j < 4; j++) acc[i][j] = (f32x4){0.f, 0.f, 0.f, 0.f};
    int wr = (w >> 1) * 64, wc = (w & 1) * 64;

    stage(Ag, As[0], 0);
    stage(Bg, Bs[0], 0);
    __syncthreads();
    int buf = 0;
    for (int kt = 0; kt < NK; ++kt) {
        if (kt + 1 < NK) { stage(Ag, As[buf ^ 1], kt + 1); stage(Bg, Bs[buf ^ 1], kt + 1); }
        short8 af[4], bfr[4];
#pragma unroll
        for (int i = 0; i < 4; i++) {
            af[i]  = *(const short8*)&As[buf][(wr + i * 16 + (l & 15)) * 32 + (l >> 4) * 8];
            bfr[i] = *(const short8*)&Bs[buf][(wc + i * 16 + (l & 15)) * 32 + (l >> 4) * 8];
        }
#pragma unroll
        for (int mi = 0; mi < 4; mi++)
#pragma unroll
            for (int ni = 0; ni < 4; ni++)
                acc[mi][ni] = mfma16(af[mi], bfr[ni], acc[mi][ni]);
        __syncthreads();
        buf ^= 1;
    }

#pragma unroll
    for (int mi = 0; mi < 4; mi++) {
#pragma unroll
        for (int ni = 0; ni < 4; ni++) {
            int col = nbase + wc + ni * 16 + (l & 15);
            float bval = (EPI != 0) ? bias[col] : 0.f;
#pragma unroll
            for (int r = 0; r < 4; r++) {
                int row = mbase + wr + mi * 16 + (l >> 4) * 4 + r;
                float v = acc[mi][ni][r];
                if (EPI == 1) {
                    size_t ridx = (size_t)row * N + col;
                    float rv = RESBF ? bf2f(((const u16*)res)[ridx]) : ((const float*)res)[ridx];
                    v += bval + rv;
                }
                if (EPI == 2) {
                    v += bval;
                    float t = tanhf(0.7978845608028654f * (v + 0.044715f * v * v * v));
                    v = 0.5f * v * (1.f + t);
                }
                if (SPLIT3) {
                    ((u16*)Cp)[(size_t)(col >> 11) * 8388608ULL + (size_t)row * 2048 + (col & 2047)] = f2bf(v);
                } else if (OUTF) {
                    ((float*)Cp)[(size_t)row * N + col] = v;
                } else {
                    ((u16*)Cp)[(size_t)row * N + col] = f2bf(v);
                }
            }
        }
    }
}

// ---------------- Causal flash attention: H=16, HD=128, S=2048, bf16 in/out ----------------
// grid: (S/64, B*H); block 256 (4 waves x 16 q-rows)
__global__ __launch_bounds__(256, 2) void attn_kernel(
    const u16* __restrict__ Q, const u16* __restrict__ Kp, const u16* __restrict__ Vp,
    u16* __restrict__ O)
{
    __shared__ u16 Ks[64 * 128];
    __shared__ u16 VT[128 * 64];
    __shared__ u16 Ps[4 * 16 * 32];
    int tid = threadIdx.x, l = tid & 63, w = tid >> 6;
    int qt = blockIdx.x, bh = blockIdx.y, b = bh >> 4, h = bh & 15;
    const float SCALE = 0.08838834764831845f; // 1/sqrt(128)
    int qbase = qt * 64;
    size_t bS = (size_t)b * 2048;

    short8 qf[4];
    {
        int qrow = qbase + w * 16 + (l & 15);
        const u16* qp = Q + (bS + qrow) * 2048 + h * 128 + (l >> 4) * 8;
#pragma unroll
        for (int ds = 0; ds < 4; ds++) qf[ds] = *(const short8*)(qp + ds * 32);
    }
    float m_[4], l_[4];
    f32x4 o_[8];
#pragma unroll
    for (int r = 0; r < 4; r++) { m_[r] = -1e30f; l_[r] = 0.f; }
#pragma unroll
    for (int d = 0; d < 8; d++) o_[d] = (f32x4){0.f, 0.f, 0.f, 0.f};

    for (int kt = 0; kt <= qt; ++kt) {
        int kbase = kt * 64;
#pragma unroll
        for (int it = 0; it < 4; ++it) {
            int slot = it * 256 + tid;
            int key = slot >> 4, dseg = slot & 15;
            const u16* kp = Kp + (bS + kbase + key) * 2048 + h * 128 + dseg * 8;
            short8 kv = *(const short8*)kp;
            int kidx = ((key * 256 + dseg * 16) ^ ((key & 7) << 4)) >> 1;
            *(short8*)&Ks[kidx] = kv;
            const u16* vp = Vp + (bS + kbase + key) * 2048 + h * 128 + dseg * 8;
            short8 vv = *(const short8*)vp;
#pragma unroll
            for (int j = 0; j < 8; j++) {
                int d = dseg * 8 + j;
                int vidx = ((d * 128 + key * 2) ^ ((d & 7) << 4)) >> 1;
                VT[vidx] = (u16)vv[j];
            }
        }
        __syncthreads();

#pragma unroll
        for (int hh = 0; hh < 2; ++hh) {
            f32x4 s0 = {0.f, 0.f, 0.f, 0.f}, s1 = {0.f, 0.f, 0.f, 0.f};
            int key0 = hh * 32 + (l & 15);
            int dl = (l >> 4) * 8;
#pragma unroll
            for (int ds = 0; ds < 4; ds++) {
                int d2 = (ds * 32 + dl) * 2;
                int i0 = ((key0 * 256 + d2) ^ ((key0 & 7) << 4)) >> 1;
                int i1 = (((key0 + 16) * 256 + d2) ^ (((key0 + 16) & 7) << 4)) >> 1;
                short8 k0v = *(const short8*)&Ks[i0];
                short8 k1v = *(const short8*)&Ks[i1];
                s0 = mfma16(qf[ds], k0v, s0);
                s1 = mfma16(qf[ds], k1v, s1);
            }
            int qr0 = qbase + w * 16 + (l >> 4) * 4;
            int kc0 = kbase + hh * 32 + (l & 15);
            float alpha[4];
#pragma unroll
            for (int r = 0; r < 4; r++) {
                float a0 = s0[r] * SCALE; if (kc0 > qr0 + r) a0 = -1e30f;
                float a1 = s1[r] * SCALE; if (kc0 + 16 > qr0 + r) a1 = -1e30f;
                float t = fmaxf(a0, a1);
                t = fmaxf(t, __shfl_xor(t, 1, 64));
                t = fmaxf(t, __shfl_xor(t, 2, 64));
                t = fmaxf(t, __shfl_xor(t, 4, 64));
                t = fmaxf(t, __shfl_xor(t, 8, 64));
                float mn = fmaxf(m_[r], t);
                alpha[r] = __expf(m_[r] - mn);
                m_[r] = mn;
                float p0 = __expf(a0 - mn), p1 = __expf(a1 - mn);
                float rs = p0 + p1;
                rs += __shfl_xor(rs, 1, 64);
                rs += __shfl_xor(rs, 2, 64);
                rs += __shfl_xor(rs, 4, 64);
                rs += __shfl_xor(rs, 8, 64);
                l_[r] = l_[r] * alpha[r] + rs;
                int prow = (l >> 4) * 4 + r;
                u16* Pw = &Ps[w * 512];
                int ia = ((prow * 64 + (l & 15) * 2) ^ ((prow & 3) << 4)) >> 1;
                int ib = ((prow * 64 + (16 + (l & 15)) * 2) ^ ((prow & 3) << 4)) >> 1;
                Pw[ia] = f2bf(p0);
                Pw[ib] = f2bf(p1);
            }
            asm volatile("s_waitcnt lgkmcnt(0)" ::: "memory");
#pragma unroll
            for (int dblk = 0; dblk < 8; dblk++)
#pragma unroll
                for (int r = 0; r < 4; r++) o_[dblk][r] *= alpha[r];
            int prow = l & 15;
            int ia = ((prow * 64 + dl * 2) ^ ((prow & 3) << 4)) >> 1;
            short8 pa = *(const short8*)&Ps[w * 512 + ia];
#pragma unroll
            for (int dblk = 0; dblk < 8; dblk++) {
                int d = dblk * 16 + (l & 15);
                int key = hh * 32 + dl;
                int iv = ((d * 128 + key * 2) ^ ((d & 7) << 4)) >> 1;
                short8 vb = *(const short8*)&VT[iv];
                o_[dblk] = mfma16(pa, vb, o_[dblk]);
            }
        }
        __syncthreads();
    }

#pragma unroll
    for (int dblk = 0; dblk < 8; dblk++) {
#pragma unroll
        for (int r = 0; r < 4; r++) {
            int qrow = qbase + w * 16 + (l >> 4) * 4 + r;
            float v = o_[dblk][r] / l_[r];
            O[(bS + qrow) * 2048 + h * 128 + dblk * 16 + (l & 15)] = f2bf(v);
        }
    }
}

extern "C" void kernel_launch(void* const* d_in, const int* in_sizes, int n_in,
                              void* d_out, int out_size, void* d_ws, size_t ws_size,
                              hipStream_t stream)
{
    const float* x    = (const float*)d_in[0];
    const float* ln1s = (const float*)d_in[1];
    const float* ln1b = (const float*)d_in[2];
    const float* Wq   = (const float*)d_in[3];
    const float* Wk   = (const float*)d_in[4];
    const float* Wv   = (const float*)d_in[5];
    const float* Wo   = (const float*)d_in[6];
    const float* bo   = (const float*)d_in[7];
    const float* ln2s = (const float*)d_in[8];
    const float* ln2b = (const float*)d_in[9];
    const float* W1   = (const float*)d_in[10];
    const float* b1   = (const float*)d_in[11];
    const float* W2   = (const float*)d_in[12];
    const float* b2   = (const float*)d_in[13];
    float* out = (float*)d_out;
    const size_t ACT = 8388608ULL; // 2*2048*2048 elems

    // ws layout (8*ACT bf16 = 134.2 MB):
    // [0,1): xn -> ctx -> xn2      [1,2): q -> x2(bf16)
    // [2,4): k,v ; [2,6): hbuf     [6,8): QKVO^T -> W1^T -> W2^T
    u16* ws16 = (u16*)d_ws;
    u16* xn   = ws16;
    u16* q    = ws16 + ACT;
    u16* k    = ws16 + 2 * ACT;
    u16* v    = ws16 + 3 * ACT;
    u16* hbuf = ws16 + 2 * ACT;
    u16* wt   = ws16 + 6 * ACT;
    u16* x2   = q; // q dead after attention

    dim3 blk(256);
    transpose_kernel<<<dim3(32, 32), blk, 0, stream>>>(Wq, wt,                 2048, 2048);
    transpose_kernel<<<dim3(32, 32), blk, 0, stream>>>(Wk, wt + (ACT >> 1),    2048, 2048);
    transpose_kernel<<<dim3(32, 32), blk, 0, stream>>>(Wv, wt + ACT,           2048, 2048);
    transpose_kernel<<<dim3(32, 32), blk, 0, stream>>>(Wo, wt + 3 * (ACT >> 1), 2048, 2048);
    ln_kernel<0><<<4096, blk, 0, stream>>>(x, ln1s, ln1b, xn);
    // fused QKV: BT = [WqT;WkT;WvT] (6144 x 2048), split outputs -> q,k,v
    gemm_bt<0, 0, 0, 1><<<dim3(48, 32), blk, 0, stream>>>(xn, wt, q, nullptr, nullptr, 4096, 6144, 2048);
    attn_kernel<<<dim3(32, 32), blk, 0, stream>>>(q, k, v, xn); // ctx -> xn
    gemm_bt<1, 0, 0, 0><<<dim3(16, 32), blk, 0, stream>>>(xn, wt + 3 * (ACT >> 1), x2, bo, x, 4096, 2048, 2048);
    transpose_kernel<<<dim3(128, 32), blk, 0, stream>>>(W1, wt, 2048, 8192); // after Wo gemm read WoT
    ln_kernel<1><<<4096, blk, 0, stream>>>(x2, ln2s, ln2b, xn); // xn2 -> xn
    gemm_bt<2, 0, 0, 0><<<dim3(64, 32), blk, 0, stream>>>(xn, wt, hbuf, b1, nullptr, 4096, 8192, 2048);
    transpose_kernel<<<dim3(32, 128), blk, 0, stream>>>(W2, wt, 8192, 2048); // after FFN1 read W1T
    gemm_bt<1, 1, 1, 0><<<dim3(16, 32), blk, 0, stream>>>(hbuf, wt, out, b2, x2, 4096, 2048, 8192);
}

// Round 5
// 798.954 us; speedup vs baseline: 2.7564x; 1.2562x over previous
//
#include <hip/hip_runtime.h>

typedef unsigned short u16;
typedef __attribute__((ext_vector_type(8))) short short8;
typedef __attribute__((ext_vector_type(8))) __bf16 bf16x8;
typedef __attribute__((ext_vector_type(4))) float f32x4;

#define DEV __device__ __forceinline__

DEV float bf2f(u16 u) {
    union { unsigned v; float f; } x; x.v = ((unsigned)u) << 16; return x.f;
}
DEV u16 f2bf(float f) {
    union { float f; unsigned v; } x; x.f = f;
    unsigned r = x.v + 0x7fff + ((x.v >> 16) & 1);
    return (u16)(r >> 16);
}

DEV f32x4 mfma16(short8 a, short8 b, f32x4 c) {
    return __builtin_amdgcn_mfma_f32_16x16x32_bf16(
        __builtin_bit_cast(bf16x8, a), __builtin_bit_cast(bf16x8, b), c, 0, 0, 0);
}

typedef const __attribute__((address_space(1))) void* gas_ptr;
typedef __attribute__((address_space(3))) void* las_ptr;

// ---------------- Transpose: f32 [R][C] -> bf16 [C][R] ----------------
__global__ __launch_bounds__(256) void transpose_kernel(
    const float* __restrict__ in, u16* __restrict__ out, int R, int C)
{
    __shared__ u16 t[64][65];
    int tid = threadIdx.x;
    int bc = blockIdx.x * 64, br = blockIdx.y * 64;
    int r = tid >> 2, cs = (tid & 3) * 16;
    const float* ip = in + (size_t)(br + r) * C + bc + cs;
    f32x4 v0 = *(const f32x4*)ip, v1 = *(const f32x4*)(ip + 4),
          v2 = *(const f32x4*)(ip + 8), v3 = *(const f32x4*)(ip + 12);
#pragma unroll
    for (int j = 0; j < 4; j++) {
        t[r][cs + j]      = f2bf(v0[j]);
        t[r][cs + 4 + j]  = f2bf(v1[j]);
        t[r][cs + 8 + j]  = f2bf(v2[j]);
        t[r][cs + 12 + j] = f2bf(v3[j]);
    }
    __syncthreads();
    int n = tid >> 2, ks = (tid & 3) * 16;
    short8 o0, o1;
#pragma unroll
    for (int j = 0; j < 8; j++) { o0[j] = (short)t[ks + j][n]; o1[j] = (short)t[ks + 8 + j][n]; }
    u16* op = out + (size_t)(bc + n) * R + br + ks;
    *(short8*)op = o0;
    *(short8*)(op + 8) = o1;
}

// ---------------- LayerNorm ----------------
template<int INBF>
__global__ __launch_bounds__(256) void ln_kernel(
    const void* __restrict__ xp, const float* __restrict__ sc, const float* __restrict__ sh,
    u16* __restrict__ out)
{
    int row = blockIdx.x, tid = threadIdx.x;
    float f[8], sum = 0.f, ss = 0.f;
    if (INBF) {
        short8 v = *(const short8*)((const u16*)xp + (size_t)row * 2048 + tid * 8);
#pragma unroll
        for (int j = 0; j < 8; j++) f[j] = bf2f((u16)v[j]);
    } else {
        const f32x4* xr = (const f32x4*)((const float*)xp + (size_t)row * 2048 + tid * 8);
        f32x4 a = xr[0], b = xr[1];
#pragma unroll
        for (int j = 0; j < 4; j++) { f[j] = a[j]; f[4 + j] = b[j]; }
    }
#pragma unroll
    for (int j = 0; j < 8; j++) { sum += f[j]; ss += f[j] * f[j]; }
#pragma unroll
    for (int m = 1; m < 64; m <<= 1) { sum += __shfl_xor(sum, m, 64); ss += __shfl_xor(ss, m, 64); }
    __shared__ float red[8];
    int w = tid >> 6, l = tid & 63;
    if (l == 0) { red[w] = sum; red[4 + w] = ss; }
    __syncthreads();
    sum = red[0] + red[1] + red[2] + red[3];
    ss  = red[4] + red[5] + red[6] + red[7];
    float mean = sum * (1.f / 2048.f);
    float var  = ss * (1.f / 2048.f) - mean * mean;
    float rstd = rsqrtf(var + 1e-5f);
    const f32x4* sp = (const f32x4*)(sc + tid * 8);
    const f32x4* bp = (const f32x4*)(sh + tid * 8);
    f32x4 s0 = sp[0], s1 = sp[1], b0 = bp[0], b1 = bp[1];
    short8 o;
#pragma unroll
    for (int j = 0; j < 4; j++) {
        o[j]     = (short)f2bf((f[j] - mean) * rstd * s0[j] + b0[j]);
        o[4 + j] = (short)f2bf((f[4 + j] - mean) * rstd * s1[j] + b1[j]);
    }
    *(short8*)(out + (size_t)row * 2048 + tid * 8) = o;
}

// ---------------- GEMM: C(MxN) = A(MxK)[bf16] * BT(NxK)[bf16] ----------------
// EPI: 0 plain, 1 +bias+residual, 2 +bias+gelu ; OUTF: f32 out ; RESBF: residual bf16
// SPLITM: 0 normal; 1 QKV split (col>>11 selects ACT-sized buffer); 2 vT split (per-b 2048x2048)
template<int EPI, int OUTF, int RESBF, int SPLITM>
__global__ __launch_bounds__(256, 2) void gemm_bt(
    const u16* __restrict__ A, const u16* __restrict__ BT, void* __restrict__ Cp,
    const float* __restrict__ bias, const void* __restrict__ res, int M, int N, int K)
{
    __shared__ u16 As[2][128 * 32];
    __shared__ u16 Bs[2][128 * 32];
    int tid = threadIdx.x, l = tid & 63, w = tid >> 6;
    int mbase = blockIdx.y * 128, nbase = blockIdx.x * 128;
    int NK = K >> 5;
    const u16* Ag = A + (size_t)mbase * K;
    const u16* Bg = BT + (size_t)nbase * K;

    auto stage = [&](const u16* G, u16* Ld, int kt) {
#pragma unroll
        for (int c = 0; c < 2; c++) {
            int slot = c * 256 + w * 64 + l;
            const u16* g = G + (size_t)(slot >> 2) * K + kt * 32 + (slot & 3) * 8;
            __builtin_amdgcn_global_load_lds((gas_ptr)g, (las_ptr)(Ld + (c * 256 + w * 64) * 8), 16, 0, 0);
        }
    };

    f32x4 acc[4][4];
#pragma unroll
    for (int i = 0; i < 4; i++)
#pragma unroll
        for (int j = 0; j < 4; j++) acc[i][j] = (f32x4){0.f, 0.f, 0.f, 0.f};
    int wr = (w >> 1) * 64, wc = (w & 1) * 64;

    stage(Ag, As[0], 0);
    stage(Bg, Bs[0], 0);
    __syncthreads();
    int buf = 0;
    for (int kt = 0; kt < NK; ++kt) {
        if (kt + 1 < NK) { stage(Ag, As[buf ^ 1], kt + 1); stage(Bg, Bs[buf ^ 1], kt + 1); }
        short8 af[4], bfr[4];
#pragma unroll
        for (int i = 0; i < 4; i++) {
            af[i]  = *(const short8*)&As[buf][(wr + i * 16 + (l & 15)) * 32 + (l >> 4) * 8];
            bfr[i] = *(const short8*)&Bs[buf][(wc + i * 16 + (l & 15)) * 32 + (l >> 4) * 8];
        }
#pragma unroll
        for (int mi = 0; mi < 4; mi++)
#pragma unroll
            for (int ni = 0; ni < 4; ni++)
                acc[mi][ni] = mfma16(af[mi], bfr[ni], acc[mi][ni]);
        __syncthreads();
        buf ^= 1;
    }

#pragma unroll
    for (int mi = 0; mi < 4; mi++) {
#pragma unroll
        for (int ni = 0; ni < 4; ni++) {
            int col = nbase + wc + ni * 16 + (l & 15);
            float bval = (EPI != 0) ? bias[col] : 0.f;
#pragma unroll
            for (int r = 0; r < 4; r++) {
                int row = mbase + wr + mi * 16 + (l >> 4) * 4 + r;
                float v = acc[mi][ni][r];
                if (EPI == 1) {
                    size_t ridx = (size_t)row * N + col;
                    float rv = RESBF ? bf2f(((const u16*)res)[ridx]) : ((const float*)res)[ridx];
                    v += bval + rv;
                }
                if (EPI == 2) {
                    v += bval;
                    float t = tanhf(0.7978845608028654f * (v + 0.044715f * v * v * v));
                    v = 0.5f * v * (1.f + t);
                }
                if (SPLITM == 1) {
                    ((u16*)Cp)[(size_t)(col >> 11) * 8388608ULL + (size_t)row * 2048 + (col & 2047)] = f2bf(v);
                } else if (SPLITM == 2) {
                    ((u16*)Cp)[(size_t)(col >> 11) * 4194304ULL + (size_t)row * 2048 + (col & 2047)] = f2bf(v);
                } else if (OUTF) {
                    ((float*)Cp)[(size_t)row * N + col] = v;
                } else {
                    ((u16*)Cp)[(size_t)row * N + col] = f2bf(v);
                }
            }
        }
    }
}

// ---------------- Causal flash attention: H=16, HD=128, S=2048 ----------------
// V input is pre-transposed: VTg[(b*16+h)*128 + d][key]
// grid: (S/64, B*H); block 256 (4 waves x 16 q-rows); heavy tiles first
__global__ __launch_bounds__(256, 2) void attn_kernel(
    const u16* __restrict__ Q, const u16* __restrict__ Kp, const u16* __restrict__ VTg,
    u16* __restrict__ O)
{
    __shared__ u16 Ks[64 * 128];
    __shared__ u16 VT[128 * 64];
    __shared__ u16 Ps[4 * 16 * 32];
    int tid = threadIdx.x, l = tid & 63, w = tid >> 6;
    int qt = (int)gridDim.x - 1 - (int)blockIdx.x;
    int bh = blockIdx.y, b = bh >> 4, h = bh & 15;
    const float SCALE = 0.08838834764831845f; // 1/sqrt(128)
    int qbase = qt * 64;
    size_t bS = (size_t)b * 2048;
    const u16* vrow = VTg + (size_t)bh * 128 * 2048;

    short8 qf[4];
    {
        int qrow = qbase + w * 16 + (l & 15);
        const u16* qp = Q + (bS + qrow) * 2048 + h * 128 + (l >> 4) * 8;
#pragma unroll
        for (int ds = 0; ds < 4; ds++) qf[ds] = *(const short8*)(qp + ds * 32);
    }
    float m_[4], l_[4];
    f32x4 o_[8];
#pragma unroll
    for (int r = 0; r < 4; r++) { m_[r] = -1e30f; l_[r] = 0.f; }
#pragma unroll
    for (int d = 0; d < 8; d++) o_[d] = (f32x4){0.f, 0.f, 0.f, 0.f};

    for (int kt = 0; kt <= qt; ++kt) {
        int kbase = kt * 64;
#pragma unroll
        for (int it = 0; it < 4; ++it) {
            int slot = it * 256 + tid;
            int key = slot >> 4, dseg = slot & 15;
            short8 kv = *(const short8*)(Kp + (bS + kbase + key) * 2048 + h * 128 + dseg * 8);
            int kidx = ((key * 256 + dseg * 16) ^ ((key & 7) << 4)) >> 1;
            *(short8*)&Ks[kidx] = kv;
            int d = slot >> 3, k8 = slot & 7;
            short8 vv = *(const short8*)(vrow + (size_t)d * 2048 + kbase + k8 * 8);
            int vidx = ((d * 128 + k8 * 16) ^ ((d & 7) << 4)) >> 1;
            *(short8*)&VT[vidx] = vv;
        }
        __syncthreads();

#pragma unroll
        for (int hh = 0; hh < 2; ++hh) {
            f32x4 s0 = {0.f, 0.f, 0.f, 0.f}, s1 = {0.f, 0.f, 0.f, 0.f};
            int key0 = hh * 32 + (l & 15);
            int dl = (l >> 4) * 8;
#pragma unroll
            for (int ds = 0; ds < 4; ds++) {
                int d2 = (ds * 32 + dl) * 2;
                int i0 = ((key0 * 256 + d2) ^ ((key0 & 7) << 4)) >> 1;
                int i1 = (((key0 + 16) * 256 + d2) ^ (((key0 + 16) & 7) << 4)) >> 1;
                short8 k0v = *(const short8*)&Ks[i0];
                short8 k1v = *(const short8*)&Ks[i1];
                s0 = mfma16(qf[ds], k0v, s0);
                s1 = mfma16(qf[ds], k1v, s1);
            }
            int qr0 = qbase + w * 16 + (l >> 4) * 4;
            int kc0 = kbase + hh * 32 + (l & 15);
            float alpha[4];
#pragma unroll
            for (int r = 0; r < 4; r++) {
                float a0 = s0[r] * SCALE; if (kc0 > qr0 + r) a0 = -1e30f;
                float a1 = s1[r] * SCALE; if (kc0 + 16 > qr0 + r) a1 = -1e30f;
                float t = fmaxf(a0, a1);
                t = fmaxf(t, __shfl_xor(t, 1, 64));
                t = fmaxf(t, __shfl_xor(t, 2, 64));
                t = fmaxf(t, __shfl_xor(t, 4, 64));
                t = fmaxf(t, __shfl_xor(t, 8, 64));
                float mn = fmaxf(m_[r], t);
                alpha[r] = __expf(m_[r] - mn);
                m_[r] = mn;
                float p0 = __expf(a0 - mn), p1 = __expf(a1 - mn);
                float rs = p0 + p1;
                rs += __shfl_xor(rs, 1, 64);
                rs += __shfl_xor(rs, 2, 64);
                rs += __shfl_xor(rs, 4, 64);
                rs += __shfl_xor(rs, 8, 64);
                l_[r] = l_[r] * alpha[r] + rs;
                int prow = (l >> 4) * 4 + r;
                u16* Pw = &Ps[w * 512];
                int ia = ((prow * 64 + (l & 15) * 2) ^ ((prow & 3) << 4)) >> 1;
                int ib = ((prow * 64 + (16 + (l & 15)) * 2) ^ ((prow & 3) << 4)) >> 1;
                Pw[ia] = f2bf(p0);
                Pw[ib] = f2bf(p1);
            }
            asm volatile("s_waitcnt lgkmcnt(0)" ::: "memory");
#pragma unroll
            for (int dblk = 0; dblk < 8; dblk++)
#pragma unroll
                for (int r = 0; r < 4; r++) o_[dblk][r] *= alpha[r];
            int prow = l & 15;
            int ia = ((prow * 64 + dl * 2) ^ ((prow & 3) << 4)) >> 1;
            short8 pa = *(const short8*)&Ps[w * 512 + ia];
#pragma unroll
            for (int dblk = 0; dblk < 8; dblk++) {
                int d = dblk * 16 + (l & 15);
                int key = hh * 32 + dl;
                int iv = ((d * 128 + key * 2) ^ ((d & 7) << 4)) >> 1;
                short8 vb = *(const short8*)&VT[iv];
                o_[dblk] = mfma16(pa, vb, o_[dblk]);
            }
        }
        __syncthreads();
    }

#pragma unroll
    for (int dblk = 0; dblk < 8; dblk++) {
#pragma unroll
        for (int r = 0; r < 4; r++) {
            int qrow = qbase + w * 16 + (l >> 4) * 4 + r;
            float v = o_[dblk][r] / l_[r];
            O[(bS + qrow) * 2048 + h * 128 + dblk * 16 + (l & 15)] = f2bf(v);
        }
    }
}

extern "C" void kernel_launch(void* const* d_in, const int* in_sizes, int n_in,
                              void* d_out, int out_size, void* d_ws, size_t ws_size,
                              hipStream_t stream)
{
    const float* x    = (const float*)d_in[0];
    const float* ln1s = (const float*)d_in[1];
    const float* ln1b = (const float*)d_in[2];
    const float* Wq   = (const float*)d_in[3];
    const float* Wk   = (const float*)d_in[4];
    const float* Wv   = (const float*)d_in[5];
    const float* Wo   = (const float*)d_in[6];
    const float* bo   = (const float*)d_in[7];
    const float* ln2s = (const float*)d_in[8];
    const float* ln2b = (const float*)d_in[9];
    const float* W1   = (const float*)d_in[10];
    const float* b1   = (const float*)d_in[11];
    const float* W2   = (const float*)d_in[12];
    const float* b2   = (const float*)d_in[13];
    float* out = (float*)d_out;
    const size_t ACT = 8388608ULL; // 2*2048*2048 elems

    // ws layout (8*ACT bf16 = 134.2 MB):
    // [0,1): xn -> ctx -> xn2      [1,2): q -> x2(bf16)
    // [2,4): k, vT ; [2,6): hbuf   [6,8): WqT,WkT,WvT,WoT -> W1T -> W2T
    u16* ws16 = (u16*)d_ws;
    u16* xn   = ws16;
    u16* q    = ws16 + ACT;
    u16* k    = ws16 + 2 * ACT;
    u16* vT   = ws16 + 3 * ACT;
    u16* hbuf = ws16 + 2 * ACT;
    u16* wt   = ws16 + 6 * ACT;
    u16* x2   = q; // q dead after attention

    dim3 blk(256);
    transpose_kernel<<<dim3(32, 32), blk, 0, stream>>>(Wq, wt,                  2048, 2048);
    transpose_kernel<<<dim3(32, 32), blk, 0, stream>>>(Wk, wt + (ACT >> 1),     2048, 2048);
    transpose_kernel<<<dim3(32, 32), blk, 0, stream>>>(Wv, wt + ACT,            2048, 2048);
    transpose_kernel<<<dim3(32, 32), blk, 0, stream>>>(Wo, wt + 3 * (ACT >> 1), 2048, 2048);
    ln_kernel<0><<<4096, blk, 0, stream>>>(x, ln1s, ln1b, xn);
    // fused QK: BT = [WqT;WkT] (4096 x 2048) -> q, k
    gemm_bt<0, 0, 0, 1><<<dim3(32, 32), blk, 0, stream>>>(xn, wt, q, nullptr, nullptr, 4096, 4096, 2048);
    // vT = WvT * xn^T: A = WvT (2048xK), BT = xn (4096 rows x K) -> vT[b][vcol][key]
    gemm_bt<0, 0, 0, 2><<<dim3(32, 16), blk, 0, stream>>>(wt + ACT, xn, vT, nullptr, nullptr, 2048, 4096, 2048);
    attn_kernel<<<dim3(32, 32), blk, 0, stream>>>(q, k, vT, xn); // ctx -> xn
    gemm_bt<1, 0, 0, 0><<<dim3(16, 32), blk, 0, stream>>>(xn, wt + 3 * (ACT >> 1), x2, bo, x, 4096, 2048, 2048);
    transpose_kernel<<<dim3(128, 32), blk, 0, stream>>>(W1, wt, 2048, 8192);
    ln_kernel<1><<<4096, blk, 0, stream>>>(x2, ln2s, ln2b, xn);
    gemm_bt<2, 0, 0, 0><<<dim3(64, 32), blk, 0, stream>>>(xn, wt, hbuf, b1, nullptr, 4096, 8192, 2048);
    transpose_kernel<<<dim3(32, 128), blk, 0, stream>>>(W2, wt, 8192, 2048);
    gemm_bt<1, 1, 1, 0><<<dim3(16, 32), blk, 0, stream>>>(hbuf, wt, out, b2, x2, 4096, 2048, 8192);
}

// Round 6
// 739.119 us; speedup vs baseline: 2.9796x; 1.0810x over previous
//
#include <hip/hip_runtime.h>

typedef unsigned short u16;
typedef __attribute__((ext_vector_type(8))) short short8;
typedef __attribute__((ext_vector_type(8))) __bf16 bf16x8;
typedef __attribute__((ext_vector_type(4))) float f32x4;

#define DEV __device__ __forceinline__

DEV float bf2f(u16 u) {
    union { unsigned v; float f; } x; x.v = ((unsigned)u) << 16; return x.f;
}
DEV u16 f2bf(float f) {
    union { float f; unsigned v; } x; x.f = f;
    unsigned r = x.v + 0x7fff + ((x.v >> 16) & 1);
    return (u16)(r >> 16);
}

DEV f32x4 mfma16(short8 a, short8 b, f32x4 c) {
    return __builtin_amdgcn_mfma_f32_16x16x32_bf16(
        __builtin_bit_cast(bf16x8, a), __builtin_bit_cast(bf16x8, b), c, 0, 0, 0);
}

typedef const __attribute__((address_space(1))) void* gas_ptr;
typedef __attribute__((address_space(3))) void* las_ptr;

// ---------------- Transpose: f32 [R][C] -> bf16 [C][R] ----------------
__global__ __launch_bounds__(256) void transpose_kernel(
    const float* __restrict__ in, u16* __restrict__ out, int R, int C)
{
    __shared__ u16 t[64][65];
    int tid = threadIdx.x;
    int bc = blockIdx.x * 64, br = blockIdx.y * 64;
    int r = tid >> 2, cs = (tid & 3) * 16;
    const float* ip = in + (size_t)(br + r) * C + bc + cs;
    f32x4 v0 = *(const f32x4*)ip, v1 = *(const f32x4*)(ip + 4),
          v2 = *(const f32x4*)(ip + 8), v3 = *(const f32x4*)(ip + 12);
#pragma unroll
    for (int j = 0; j < 4; j++) {
        t[r][cs + j]      = f2bf(v0[j]);
        t[r][cs + 4 + j]  = f2bf(v1[j]);
        t[r][cs + 8 + j]  = f2bf(v2[j]);
        t[r][cs + 12 + j] = f2bf(v3[j]);
    }
    __syncthreads();
    int n = tid >> 2, ks = (tid & 3) * 16;
    short8 o0, o1;
#pragma unroll
    for (int j = 0; j < 8; j++) { o0[j] = (short)t[ks + j][n]; o1[j] = (short)t[ks + 8 + j][n]; }
    u16* op = out + (size_t)(bc + n) * R + br + ks;
    *(short8*)op = o0;
    *(short8*)(op + 8) = o1;
}

// ---------------- LayerNorm ----------------
template<int INBF>
__global__ __launch_bounds__(256) void ln_kernel(
    const void* __restrict__ xp, const float* __restrict__ sc, const float* __restrict__ sh,
    u16* __restrict__ out)
{
    int row = blockIdx.x, tid = threadIdx.x;
    float f[8], sum = 0.f, ss = 0.f;
    if (INBF) {
        short8 v = *(const short8*)((const u16*)xp + (size_t)row * 2048 + tid * 8);
#pragma unroll
        for (int j = 0; j < 8; j++) f[j] = bf2f((u16)v[j]);
    } else {
        const f32x4* xr = (const f32x4*)((const float*)xp + (size_t)row * 2048 + tid * 8);
        f32x4 a = xr[0], b = xr[1];
#pragma unroll
        for (int j = 0; j < 4; j++) { f[j] = a[j]; f[4 + j] = b[j]; }
    }
#pragma unroll
    for (int j = 0; j < 8; j++) { sum += f[j]; ss += f[j] * f[j]; }
#pragma unroll
    for (int m = 1; m < 64; m <<= 1) { sum += __shfl_xor(sum, m, 64); ss += __shfl_xor(ss, m, 64); }
    __shared__ float red[8];
    int w = tid >> 6, l = tid & 63;
    if (l == 0) { red[w] = sum; red[4 + w] = ss; }
    __syncthreads();
    sum = red[0] + red[1] + red[2] + red[3];
    ss  = red[4] + red[5] + red[6] + red[7];
    float mean = sum * (1.f / 2048.f);
    float var  = ss * (1.f / 2048.f) - mean * mean;
    float rstd = rsqrtf(var + 1e-5f);
    const f32x4* sp = (const f32x4*)(sc + tid * 8);
    const f32x4* bp = (const f32x4*)(sh + tid * 8);
    f32x4 s0 = sp[0], s1 = sp[1], b0 = bp[0], b1 = bp[1];
    short8 o;
#pragma unroll
    for (int j = 0; j < 4; j++) {
        o[j]     = (short)f2bf((f[j] - mean) * rstd * s0[j] + b0[j]);
        o[4 + j] = (short)f2bf((f[4 + j] - mean) * rstd * s1[j] + b1[j]);
    }
    *(short8*)(out + (size_t)row * 2048 + tid * 8) = o;
}

// ---------------- GEMM: C(MxN) = A(MxK)[bf16] * BT(NxK)[bf16] ----------------
// EPI: 0 plain, 1 +bias+residual, 2 +bias+gelu ; OUTF: f32 out ; RESBF: residual bf16
// SPLITM: 0 normal; 1 QKV split (col>>11 selects ACT buffer); 2 vT split (per-b 2048x2048)
template<int EPI, int OUTF, int RESBF, int SPLITM>
__global__ __launch_bounds__(256, 2) void gemm_bt(
    const u16* __restrict__ A, const u16* __restrict__ BT, void* __restrict__ Cp,
    const float* __restrict__ bias, const void* __restrict__ res, int M, int N, int K)
{
    __shared__ u16 As[2][128 * 32];
    __shared__ u16 Bs[2][128 * 32];
    int tid = threadIdx.x, l = tid & 63, w = tid >> 6;
    int mbase = blockIdx.y * 128, nbase = blockIdx.x * 128;
    int NK = K >> 5;
    const u16* Ag = A + (size_t)mbase * K;
    const u16* Bg = BT + (size_t)nbase * K;

    auto stage = [&](const u16* G, u16* Ld, int kt) {
#pragma unroll
        for (int c = 0; c < 2; c++) {
            int slot = c * 256 + w * 64 + l;
            const u16* g = G + (size_t)(slot >> 2) * K + kt * 32 + (slot & 3) * 8;
            __builtin_amdgcn_global_load_lds((gas_ptr)g, (las_ptr)(Ld + (c * 256 + w * 64) * 8), 16, 0, 0);
        }
    };

    f32x4 acc[4][4];
#pragma unroll
    for (int i = 0; i < 4; i++)
#pragma unroll
        for (int j = 0; j < 4; j++) acc[i][j] = (f32x4){0.f, 0.f, 0.f, 0.f};
    int wr = (w >> 1) * 64, wc = (w & 1) * 64;

    stage(Ag, As[0], 0);
    stage(Bg, Bs[0], 0);
    __syncthreads();
    int buf = 0;
    for (int kt = 0; kt < NK; ++kt) {
        if (kt + 1 < NK) { stage(Ag, As[buf ^ 1], kt + 1); stage(Bg, Bs[buf ^ 1], kt + 1); }
        short8 af[4], bfr[4];
#pragma unroll
        for (int i = 0; i < 4; i++) {
            af[i]  = *(const short8*)&As[buf][(wr + i * 16 + (l & 15)) * 32 + (l >> 4) * 8];
            bfr[i] = *(const short8*)&Bs[buf][(wc + i * 16 + (l & 15)) * 32 + (l >> 4) * 8];
        }
#pragma unroll
        for (int mi = 0; mi < 4; mi++)
#pragma unroll
            for (int ni = 0; ni < 4; ni++)
                acc[mi][ni] = mfma16(af[mi], bfr[ni], acc[mi][ni]);
        __syncthreads();
        buf ^= 1;
    }

#pragma unroll
    for (int mi = 0; mi < 4; mi++) {
#pragma unroll
        for (int ni = 0; ni < 4; ni++) {
            int col = nbase + wc + ni * 16 + (l & 15);
            float bval = (EPI != 0) ? bias[col] : 0.f;
#pragma unroll
            for (int r = 0; r < 4; r++) {
                int row = mbase + wr + mi * 16 + (l >> 4) * 4 + r;
                float v = acc[mi][ni][r];
                if (EPI == 1) {
                    size_t ridx = (size_t)row * N + col;
                    float rv = RESBF ? bf2f(((const u16*)res)[ridx]) : ((const float*)res)[ridx];
                    v += bval + rv;
                }
                if (EPI == 2) {
                    v += bval;
                    float t = tanhf(0.7978845608028654f * (v + 0.044715f * v * v * v));
                    v = 0.5f * v * (1.f + t);
                }
                if (SPLITM == 1) {
                    ((u16*)Cp)[(size_t)(col >> 11) * 8388608ULL + (size_t)row * 2048 + (col & 2047)] = f2bf(v);
                } else if (SPLITM == 2) {
                    ((u16*)Cp)[(size_t)(col >> 11) * 4194304ULL + (size_t)row * 2048 + (col & 2047)] = f2bf(v);
                } else if (OUTF) {
                    ((float*)Cp)[(size_t)row * N + col] = v;
                } else {
                    ((u16*)Cp)[(size_t)row * N + col] = f2bf(v);
                }
            }
        }
    }
}

// ---------------- Causal flash attention: H=16, HD=128, S=2048 ----------------
// QBLK=128: 4 waves x 32 q-rows (2 m-groups of 16). KVBLK=64. Merged 64-key softmax.
// V pre-transposed in global: VTg[(b*16+h)*128 + d][key]
// grid: (S/128, B*H); block 256; heavy tiles first
__global__ __launch_bounds__(256, 2) void attn_kernel(
    const u16* __restrict__ Q, const u16* __restrict__ Kp, const u16* __restrict__ VTg,
    u16* __restrict__ O)
{
    __shared__ u16 Ks[64 * 128];   // [key][d], slot-XOR swizzled
    __shared__ u16 VT[128 * 64];   // [d][key], slot-XOR swizzled
    __shared__ u16 Ps[4 * 2048];   // per-wave P fragment buffer [mg][kk][lane][8]
    int tid = threadIdx.x, l = tid & 63, w = tid >> 6;
    int qtl = (int)gridDim.x - 1 - (int)blockIdx.x;
    int bh = blockIdx.y, b = bh >> 4, h = bh & 15;
    const float SCALE = 0.08838834764831845f; // 1/sqrt(128)
    int qbase = qtl * 128;
    size_t bS = (size_t)b * 2048;
    const u16* vrow = VTg + (size_t)bh * 128 * 2048;

    // Q fragments: qf[mg][ds], row = qbase + w*32 + mg*16 + (l&15), d = ds*32 + (l>>4)*8
    short8 qf[2][4];
#pragma unroll
    for (int mg = 0; mg < 2; mg++) {
        int qrow = qbase + w * 32 + mg * 16 + (l & 15);
        const u16* qp = Q + (bS + qrow) * 2048 + h * 128 + (l >> 4) * 8;
#pragma unroll
        for (int ds = 0; ds < 4; ds++) qf[mg][ds] = *(const short8*)(qp + ds * 32);
    }
    float m_[2][4], l_[2][4];
    f32x4 o_[2][8];
#pragma unroll
    for (int mg = 0; mg < 2; mg++)
#pragma unroll
        for (int r = 0; r < 4; r++) { m_[mg][r] = -1e30f; l_[mg][r] = 0.f; }
#pragma unroll
    for (int mg = 0; mg < 2; mg++)
#pragma unroll
        for (int d = 0; d < 8; d++) o_[mg][d] = (f32x4){0.f, 0.f, 0.f, 0.f};

    int ktmax = 2 * qtl + 1;
    for (int kt = 0; kt <= ktmax; ++kt) {
        int kbase = kt * 64;
        // ---- stage K (64x128) and V^T (128x64) ----
#pragma unroll
        for (int it = 0; it < 4; ++it) {
            int slot = it * 256 + tid;
            int key = slot >> 4, dseg = slot & 15;
            short8 kv = *(const short8*)(Kp + (bS + kbase + key) * 2048 + h * 128 + dseg * 8);
            int kidx = ((key * 256 + dseg * 16) ^ ((key & 7) << 4)) >> 1;
            *(short8*)&Ks[kidx] = kv;
            int d = slot >> 3, k8 = slot & 7;
            short8 vv = *(const short8*)(vrow + (size_t)d * 2048 + kbase + k8 * 8);
            int vidx = ((d * 128 + k8 * 16) ^ ((d & 7) << 4)) >> 1;
            *(short8*)&VT[vidx] = vv;
        }
        __syncthreads();

        // ---- QK^T: 64 keys at once ----
        f32x4 s[2][4];
#pragma unroll
        for (int mg = 0; mg < 2; mg++)
#pragma unroll
            for (int kg = 0; kg < 4; kg++) s[mg][kg] = (f32x4){0.f, 0.f, 0.f, 0.f};
        __builtin_amdgcn_s_setprio(1);
#pragma unroll
        for (int kg = 0; kg < 4; kg++) {
            int key0 = kg * 16 + (l & 15);
#pragma unroll
            for (int ds = 0; ds < 4; ds++) {
                int i0 = ((key0 * 256 + ds * 64 + (l >> 4) * 16) ^ ((key0 & 7) << 4)) >> 1;
                short8 kb = *(const short8*)&Ks[i0];
                s[0][kg] = mfma16(qf[0][ds], kb, s[0][kg]);
                s[1][kg] = mfma16(qf[1][ds], kb, s[1][kg]);
            }
        }
        __builtin_amdgcn_s_setprio(0);

        // ---- merged online softmax over 64 keys ----
        bool domask = (kbase + 63) > qbase;
        float alpha[2][4];
        u16* Pw = &Ps[w * 2048];
#pragma unroll
        for (int mg = 0; mg < 2; mg++) {
#pragma unroll
            for (int r = 0; r < 4; r++) {
                int qrow = qbase + w * 32 + mg * 16 + (l >> 4) * 4 + r;
                float aa[4];
#pragma unroll
                for (int kg = 0; kg < 4; kg++) {
                    float a = s[mg][kg][r] * SCALE;
                    if (domask && (kbase + kg * 16 + (l & 15)) > qrow) a = -1e30f;
                    aa[kg] = a;
                }
                float mx = fmaxf(fmaxf(aa[0], aa[1]), fmaxf(aa[2], aa[3]));
                mx = fmaxf(mx, __shfl_xor(mx, 1, 64));
                mx = fmaxf(mx, __shfl_xor(mx, 2, 64));
                mx = fmaxf(mx, __shfl_xor(mx, 4, 64));
                mx = fmaxf(mx, __shfl_xor(mx, 8, 64));
                float mn = fmaxf(m_[mg][r], mx);
                float al = __expf(m_[mg][r] - mn);
                m_[mg][r] = mn;
                float p[4], rs = 0.f;
#pragma unroll
                for (int kg = 0; kg < 4; kg++) { p[kg] = __expf(aa[kg] - mn); rs += p[kg]; }
                rs += __shfl_xor(rs, 1, 64);
                rs += __shfl_xor(rs, 2, 64);
                rs += __shfl_xor(rs, 4, 64);
                rs += __shfl_xor(rs, 8, 64);
                l_[mg][r] = l_[mg][r] * al + rs;
                alpha[mg][r] = al;
                // write P into fragment-linear buffer: [mg][kk=col>>5][lane'][col&7]
#pragma unroll
                for (int kg = 0; kg < 4; kg++) {
                    int col = kg * 16 + (l & 15);
                    int lp = ((l >> 4) * 4 + r) | (((col >> 3) & 3) << 4);
                    Pw[(mg * 2 + (col >> 5)) * 512 + lp * 8 + (col & 7)] = f2bf(p[kg]);
                }
            }
        }
        // rescale O
#pragma unroll
        for (int mg = 0; mg < 2; mg++)
#pragma unroll
            for (int dblk = 0; dblk < 8; dblk++)
#pragma unroll
                for (int r = 0; r < 4; r++) o_[mg][dblk][r] *= alpha[mg][r];

        // ---- PV ----
        __builtin_amdgcn_s_setprio(1);
#pragma unroll
        for (int kk = 0; kk < 2; kk++) {
            short8 pa0 = *(const short8*)&Pw[(0 * 2 + kk) * 512 + l * 8];
            short8 pa1 = *(const short8*)&Pw[(1 * 2 + kk) * 512 + l * 8];
#pragma unroll
            for (int dblk = 0; dblk < 8; dblk++) {
                int d = dblk * 16 + (l & 15);
                int iv = ((d * 128 + kk * 64 + (l >> 4) * 16) ^ ((d & 7) << 4)) >> 1;
                short8 vb = *(const short8*)&VT[iv];
                o_[0][dblk] = mfma16(pa0, vb, o_[0][dblk]);
                o_[1][dblk] = mfma16(pa1, vb, o_[1][dblk]);
            }
        }
        __builtin_amdgcn_s_setprio(0);
        __syncthreads();
    }

#pragma unroll
    for (int mg = 0; mg < 2; mg++) {
#pragma unroll
        for (int dblk = 0; dblk < 8; dblk++) {
#pragma unroll
            for (int r = 0; r < 4; r++) {
                int qrow = qbase + w * 32 + mg * 16 + (l >> 4) * 4 + r;
                float v = o_[mg][dblk][r] / l_[mg][r];
                O[(bS + qrow) * 2048 + h * 128 + dblk * 16 + (l & 15)] = f2bf(v);
            }
        }
    }
}

extern "C" void kernel_launch(void* const* d_in, const int* in_sizes, int n_in,
                              void* d_out, int out_size, void* d_ws, size_t ws_size,
                              hipStream_t stream)
{
    const float* x    = (const float*)d_in[0];
    const float* ln1s = (const float*)d_in[1];
    const float* ln1b = (const float*)d_in[2];
    const float* Wq   = (const float*)d_in[3];
    const float* Wk   = (const float*)d_in[4];
    const float* Wv   = (const float*)d_in[5];
    const float* Wo   = (const float*)d_in[6];
    const float* bo   = (const float*)d_in[7];
    const float* ln2s = (const float*)d_in[8];
    const float* ln2b = (const float*)d_in[9];
    const float* W1   = (const float*)d_in[10];
    const float* b1   = (const float*)d_in[11];
    const float* W2   = (const float*)d_in[12];
    const float* b2   = (const float*)d_in[13];
    float* out = (float*)d_out;
    const size_t ACT = 8388608ULL; // 2*2048*2048 elems

    u16* ws16 = (u16*)d_ws;
    u16* xn   = ws16;
    u16* q    = ws16 + ACT;
    u16* k    = ws16 + 2 * ACT;
    u16* vT   = ws16 + 3 * ACT;
    u16* hbuf = ws16 + 2 * ACT;
    u16* wt   = ws16 + 6 * ACT;
    u16* x2   = q; // q dead after attention

    dim3 blk(256);
    transpose_kernel<<<dim3(32, 32), blk, 0, stream>>>(Wq, wt,                  2048, 2048);
    transpose_kernel<<<dim3(32, 32), blk, 0, stream>>>(Wk, wt + (ACT >> 1),     2048, 2048);
    transpose_kernel<<<dim3(32, 32), blk, 0, stream>>>(Wv, wt + ACT,            2048, 2048);
    transpose_kernel<<<dim3(32, 32), blk, 0, stream>>>(Wo, wt + 3 * (ACT >> 1), 2048, 2048);
    ln_kernel<0><<<4096, blk, 0, stream>>>(x, ln1s, ln1b, xn);
    // fused QK: BT = [WqT;WkT] (4096 x 2048) -> q, k
    gemm_bt<0, 0, 0, 1><<<dim3(32, 32), blk, 0, stream>>>(xn, wt, q, nullptr, nullptr, 4096, 4096, 2048);
    // vT = WvT * xn^T -> vT[b][d][s]
    gemm_bt<0, 0, 0, 2><<<dim3(32, 16), blk, 0, stream>>>(wt + ACT, xn, vT, nullptr, nullptr, 2048, 4096, 2048);
    attn_kernel<<<dim3(16, 32), blk, 0, stream>>>(q, k, vT, xn); // ctx -> xn
    gemm_bt<1, 0, 0, 0><<<dim3(16, 32), blk, 0, stream>>>(xn, wt + 3 * (ACT >> 1), x2, bo, x, 4096, 2048, 2048);
    transpose_kernel<<<dim3(128, 32), blk, 0, stream>>>(W1, wt, 2048, 8192);
    ln_kernel<1><<<4096, blk, 0, stream>>>(x2, ln2s, ln2b, xn);
    gemm_bt<2, 0, 0, 0><<<dim3(64, 32), blk, 0, stream>>>(xn, wt, hbuf, b1, nullptr, 4096, 8192, 2048);
    transpose_kernel<<<dim3(32, 128), blk, 0, stream>>>(W2, wt, 8192, 2048);
    gemm_bt<1, 1, 1, 0><<<dim3(16, 32), blk, 0, stream>>>(hbuf, wt, out, b2, x2, 4096, 2048, 8192);
}